// Round 4
// baseline (58.114 us; speedup 1.0000x reference)
//
#include <hip/hip_runtime.h>
#include <hip/hip_bf16.h>
#include <stdint.h>

// B=4, C=256, H=W=64 -> L=4096, POS=16384; n_mem=64, sqrt_fin=16, scale=1/4.
using bf16 = __hip_bfloat16;
typedef __attribute__((ext_vector_type(8))) short bf16x8;
typedef __attribute__((ext_vector_type(4))) float f32x4;

#define CDIM 256
#define LDIM 4096

__device__ __forceinline__ void gload16(void* lds, const void* g) {
  auto* l3 = (__attribute__((address_space(3))) char*)(uintptr_t)lds;
  auto* g1 = (const __attribute__((address_space(1))) char*)(uintptr_t)g;
  __builtin_amdgcn_global_load_lds((const __attribute__((address_space(1))) void*)g1,
                                   (__attribute__((address_space(3))) void*)l3, 16, 0, 0);
}

template <int CTRL>
__device__ __forceinline__ float dpp_add(float v) {
  int p = __builtin_amdgcn_update_dpp(0, __float_as_int(v), CTRL, 0xf, 0xf, true);
  return v + __int_as_float(p);
}

__device__ __forceinline__ float b2f(short h) {
  return __uint_as_float(((uint32_t)(uint16_t)h) << 16);
}

// ---------- P: weight casts + MmB + x transpose (one launch) ----------
__global__ void prep_kernel(const float* __restrict__ x,
                            const float* __restrict__ Wq, const float* __restrict__ Wk,
                            const float* __restrict__ v, const float* __restrict__ Wo,
                            bf16* __restrict__ Wqb, bf16* __restrict__ Wkb,
                            bf16* __restrict__ MmBg, bf16* __restrict__ Xt) {
  int bid = blockIdx.x, t = threadIdx.x;
  if (bid < 512) {
    const float* src = (bid < 256) ? Wq : Wk;
    bf16* dst = (bid < 256) ? Wqb : Wkb;
    int base = (bid & 255) * 1024 + t * 4;
    float4 f = *(const float4*)(src + base);
    dst[base + 0] = __float2bfloat16(f.x);
    dst[base + 1] = __float2bfloat16(f.y);
    dst[base + 2] = __float2bfloat16(f.z);
    dst[base + 3] = __float2bfloat16(f.w);
  } else if (bid < 768) {
    __shared__ float red[256];
    int o = bid - 512;
    int n = t >> 2, cg = t & 3;
    const float* vr = v + n * CDIM + cg * 64;
    const float* wr = Wo + o * CDIM + cg * 64;
    float a = 0.f;
    for (int c = 0; c < 64; c++) a += vr[c] * wr[c];
    red[t] = a;
    __syncthreads();
    if (t < 64)
      MmBg[o * 64 + t] =
          __float2bfloat16(red[t * 4] + red[t * 4 + 1] + red[t * 4 + 2] + red[t * 4 + 3]);
  } else {
    __shared__ float tile[64][65];
    int tb = bid - 768;
    int l0 = (tb & 63) * 64, c0 = ((tb >> 6) & 3) * 64, b = tb >> 8;
    const float* xb = x + ((size_t)b * CDIM + c0) * LDIM + l0;
#pragma unroll
    for (int k = 0; k < 4; k++) {
      int idx = k * 256 + t;
      int c = idx >> 4, l4 = (idx & 15) * 4;
      float4 f = *(const float4*)(xb + (size_t)c * LDIM + l4);
      tile[c][l4 + 0] = f.x;
      tile[c][l4 + 1] = f.y;
      tile[c][l4 + 2] = f.z;
      tile[c][l4 + 3] = f.w;
    }
    __syncthreads();
    bf16* xo = Xt + ((size_t)b * LDIM + l0) * CDIM + c0;
#pragma unroll
    for (int k = 0; k < 2; k++) {
      int idx = k * 256 + t;
      int l = idx >> 3, c8 = idx & 7;
      bf16 hv[8];
#pragma unroll
      for (int j = 0; j < 8; j++) hv[j] = __float2bfloat16(tile[c8 * 8 + j][l]);
      *(uint4*)((char*)(xo + (size_t)l * CDIM + c8 * 8)) = *(const uint4*)hv;
    }
  }
}

// ---------- A: q-projection GEMM 128x256, BK=64 -> qpart[pos][s][4] ----------
__global__ __launch_bounds__(256) void gemm_q(const bf16* __restrict__ Xt,
                                              const bf16* __restrict__ Wqb,
                                              const float* __restrict__ bq,
                                              bf16* __restrict__ qpart) {
  __shared__ __align__(16) char smem[49152];  // As 16K @0, Bs 32K @16384
  char* As = smem;
  char* Bs = smem + 16384;
  const int t = threadIdx.x, lane = t & 63, w = t >> 6;
  const int wm = w >> 1, wn = w & 1, s = lane & 15, g = lane >> 4;
  const int pos0 = blockIdx.x * 128, o0 = blockIdx.y * 256;

  f32x4 acc[4][8] = {};
  for (int kt = 0; kt < 4; kt++) {
    __syncthreads();
#pragma unroll
    for (int j = 0; j < 4; j++) {  // As: 128 rows x 128B
      int Pb = (j * 4 + w) * 64;
      int P = Pb + lane;
      int row = P >> 3, u = P & 7;
      gload16(As + Pb * 16, (const char*)Xt + (size_t)(pos0 + row) * 512 + kt * 128 + u * 16);
    }
#pragma unroll
    for (int j = 0; j < 8; j++) {  // Bs: 256 rows x 128B
      int Pb = (j * 4 + w) * 64;
      int P = Pb + lane;
      int row = P >> 3, u = P & 7;
      gload16(Bs + Pb * 16, (const char*)Wqb + (size_t)(o0 + row) * 512 + kt * 128 + u * 16);
    }
    asm volatile("s_waitcnt vmcnt(0) lgkmcnt(0)" ::: "memory");
    __syncthreads();
#pragma unroll
    for (int k2 = 0; k2 < 2; k2++) {
      bf16x8 af[4], bfr[8];
#pragma unroll
      for (int mf = 0; mf < 4; mf++)
        af[mf] = *(const bf16x8*)(As + (wm * 64 + mf * 16 + s) * 128 + k2 * 64 + g * 16);
#pragma unroll
      for (int nf = 0; nf < 8; nf++)
        bfr[nf] = *(const bf16x8*)(Bs + (wn * 128 + nf * 16 + s) * 128 + k2 * 64 + g * 16);
#pragma unroll
      for (int mf = 0; mf < 4; mf++)
#pragma unroll
        for (int nf = 0; nf < 8; nf++)
          acc[mf][nf] = __builtin_amdgcn_mfma_f32_16x16x32_bf16(af[mf], bfr[nf], acc[mf][nf], 0, 0, 0);
    }
  }
  float bqv[8];
#pragma unroll
  for (int nf = 0; nf < 8; nf++) bqv[nf] = bq[o0 + wn * 128 + nf * 16 + s];
  __syncthreads();  // done with As/Bs fragment reads; reuse As as qLDS
  float* qLDS = (float*)smem;  // [128 pos][16 s][2 wn] f32 = 16KB
#pragma unroll
  for (int mf = 0; mf < 4; mf++)
#pragma unroll
    for (int r = 0; r < 4; r++) {
      float qp = 0.f;
#pragma unroll
      for (int nf = 0; nf < 8; nf++) qp += fmaxf(acc[mf][nf][r] + bqv[nf], 0.f);
      int pos_l = wm * 64 + mf * 16 + g * 4 + r;
      qLDS[(pos_l * 16 + s) * 2 + wn] = qp * 0.00390625f;  // (1/4)/64
    }
  __syncthreads();
#pragma unroll
  for (int j = 0; j < 8; j++) {
    int idx = j * 256 + t;  // 2048 = 128 pos x 16 s
    float v2 = qLDS[idx * 2] + qLDS[idx * 2 + 1];
    int pos_l = idx >> 4, ss = idx & 15;
    qpart[((size_t)(pos0 + pos_l) * 16 + ss) * 4 + blockIdx.y] = __float2bfloat16(v2);
  }
}

// ---------- B: k-projection GEMM 128x128 + qsum merge + DPP s-reduce -> pooled ----------
__global__ __launch_bounds__(256) void gemm_k(const bf16* __restrict__ Xt,
                                              const bf16* __restrict__ Wkb,
                                              const float* __restrict__ bk,
                                              const bf16* __restrict__ qpart,
                                              bf16* __restrict__ pooled) {
  __shared__ __align__(16) char smem[40960];  // As 16K, Bs 16K, qsumLDS 8K
  char* As = smem;
  char* Bs = smem + 16384;
  float* qsumLDS = (float*)(smem + 32768);  // [128 pos][16 s]
  const int t = threadIdx.x, lane = t & 63, w = t >> 6;
  const int wm = w >> 1, wn = w & 1, s = lane & 15, g = lane >> 4;
  const int pos0 = blockIdx.x * 128, o0 = blockIdx.y * 128;

#pragma unroll
  for (int j = 0; j < 8; j++) {
    int idx = j * 256 + t;
    short4 qq = *(const short4*)((const char*)qpart +
                                 ((size_t)(pos0 + (idx >> 4)) * 16 + (idx & 15)) * 8);
    qsumLDS[idx] = b2f(qq.x) + b2f(qq.y) + b2f(qq.z) + b2f(qq.w);
  }

  f32x4 acc[4][4] = {};
  for (int kt = 0; kt < 4; kt++) {
    __syncthreads();
#pragma unroll
    for (int j = 0; j < 4; j++) {  // As
      int Pb = (j * 4 + w) * 64;
      int P = Pb + lane;
      int row = P >> 3, u = P & 7;
      gload16(As + Pb * 16, (const char*)Xt + (size_t)(pos0 + row) * 512 + kt * 128 + u * 16);
    }
#pragma unroll
    for (int j = 0; j < 4; j++) {  // Bs: 128 rows
      int Pb = (j * 4 + w) * 64;
      int P = Pb + lane;
      int row = P >> 3, u = P & 7;
      gload16(Bs + Pb * 16, (const char*)Wkb + (size_t)(o0 + row) * 512 + kt * 128 + u * 16);
    }
    asm volatile("s_waitcnt vmcnt(0) lgkmcnt(0)" ::: "memory");
    __syncthreads();
#pragma unroll
    for (int k2 = 0; k2 < 2; k2++) {
      bf16x8 af[4], bfr[4];
#pragma unroll
      for (int mf = 0; mf < 4; mf++)
        af[mf] = *(const bf16x8*)(As + (wm * 64 + mf * 16 + s) * 128 + k2 * 64 + g * 16);
#pragma unroll
      for (int nf = 0; nf < 4; nf++)
        bfr[nf] = *(const bf16x8*)(Bs + (wn * 64 + nf * 16 + s) * 128 + k2 * 64 + g * 16);
#pragma unroll
      for (int mf = 0; mf < 4; mf++)
#pragma unroll
        for (int nf = 0; nf < 4; nf++)
          acc[mf][nf] = __builtin_amdgcn_mfma_f32_16x16x32_bf16(af[mf], bfr[nf], acc[mf][nf], 0, 0, 0);
    }
  }
  float bkv[4];
#pragma unroll
  for (int nf = 0; nf < 4; nf++) bkv[nf] = bk[o0 + wn * 64 + nf * 16 + s];
#pragma unroll
  for (int mf = 0; mf < 4; mf++)
#pragma unroll
    for (int r = 0; r < 4; r++) {
      int pos_l = wm * 64 + mf * 16 + g * 4 + r;
      float qv = qsumLDS[pos_l * 16 + s];
      float red[4];
#pragma unroll
      for (int nf = 0; nf < 4; nf++) {
        float tt = qv * fmaxf(acc[mf][nf][r] + bkv[nf], 0.f);
        tt = dpp_add<0x128>(tt);  // row_ror:8
        tt = dpp_add<0x124>(tt);  // row_ror:4
        tt = dpp_add<0x122>(tt);  // row_ror:2
        tt = dpp_add<0x121>(tt);  // row_ror:1
        red[nf] = tt;
      }
      float v01 = (s & 1) ? red[1] : red[0];
      float v23 = (s & 1) ? red[3] : red[2];
      float val = (s & 2) ? v23 : v01;
      if (s < 4)
        pooled[(size_t)(pos0 + pos_l) * 64 + blockIdx.y * 8 + wn * 4 + s] = __float2bfloat16(val);
    }
}

// ---------- C: out = x + pooled @ MmB + bo ----------
__global__ __launch_bounds__(512) void out_kernel(const bf16* __restrict__ pooled,
                                                  const bf16* __restrict__ MmBg,
                                                  const float* __restrict__ bo,
                                                  const float* __restrict__ x,
                                                  float* __restrict__ out) {
  __shared__ __align__(16) char smem[40960];  // Mlds 32K @0, Plds 8K @32768
  char* Mlds = smem;
  char* Plds = smem + 32768;
  const int t = threadIdx.x, lane = t & 63, w = t >> 6;
  const int s = lane & 15, g = lane >> 4;
  const int pos0 = blockIdx.x * 64;
#pragma unroll
  for (int j = 0; j < 4; j++) {
    int P = j * 512 + t;
    int row = P >> 3, u = P & 7;
    uint4 vv = *(const uint4*)((const char*)MmBg + row * 128 + u * 16);
    *(uint4*)(Mlds + row * 128 + ((u ^ (row & 7)) * 16)) = vv;
  }
  {
    int row = t >> 3, u = t & 7;
    uint4 vv = *(const uint4*)((const char*)pooled + (size_t)(pos0 + row) * 128 + u * 16);
    *(uint4*)(Plds + row * 128 + ((u ^ (row & 7)) * 16)) = vv;
  }
  __syncthreads();
  f32x4 oacc[2][4] = {};
#pragma unroll
  for (int kt = 0; kt < 2; kt++) {
    bf16x8 pf[4];
#pragma unroll
    for (int nfp = 0; nfp < 4; nfp++) {
      int prow = nfp * 16 + s;
      pf[nfp] = *(const bf16x8*)(Plds + prow * 128 + (((kt * 4 + g) ^ (prow & 7)) * 16));
    }
#pragma unroll
    for (int mfo = 0; mfo < 2; mfo++) {
      int mrow = w * 32 + mfo * 16 + s;
      bf16x8 mfr = *(const bf16x8*)(Mlds + mrow * 128 + (((kt * 4 + g) ^ (mrow & 7)) * 16));
#pragma unroll
      for (int nfp = 0; nfp < 4; nfp++)
        oacc[mfo][nfp] = __builtin_amdgcn_mfma_f32_16x16x32_bf16(mfr, pf[nfp], oacc[mfo][nfp], 0, 0, 0);
    }
  }
  const int b = pos0 >> 12, l0 = pos0 & (LDIM - 1);
#pragma unroll
  for (int mfo = 0; mfo < 2; mfo++)
#pragma unroll
    for (int r = 0; r < 4; r++) {
      int o2 = w * 32 + mfo * 16 + g * 4 + r;
      float bov = bo[o2];
      const float* xr = x + ((size_t)(b * CDIM + o2) * LDIM) + l0;
      float* orow = out + ((size_t)(b * CDIM + o2) * LDIM) + l0;
#pragma unroll
      for (int nfp = 0; nfp < 4; nfp++) {
        int p = nfp * 16 + s;
        orow[p] = xr[p] + oacc[mfo][nfp][r] + bov;
      }
    }
}

extern "C" void kernel_launch(void* const* d_in, const int* in_sizes, int n_in,
                              void* d_out, int out_size, void* d_ws, size_t ws_size,
                              hipStream_t stream) {
  (void)in_sizes; (void)n_in; (void)out_size; (void)ws_size;
  const float* x = (const float*)d_in[0];
  const float* Wq = (const float*)d_in[1];
  const float* bq = (const float*)d_in[2];
  const float* Wk = (const float*)d_in[3];
  const float* bk = (const float*)d_in[4];
  const float* v = (const float*)d_in[5];
  const float* Wo = (const float*)d_in[6];
  const float* bo = (const float*)d_in[7];
  float* out = (float*)d_out;

  char* ws = (char*)d_ws;
  bf16* Xt = (bf16*)ws;                    // 8,388,608
  bf16* Wqb = (bf16*)(ws + 8388608);       // 524,288
  bf16* Wkb = (bf16*)(ws + 8912896);       // 524,288
  bf16* MmBg = (bf16*)(ws + 9437184);      // 32,768
  bf16* qpart = (bf16*)(ws + 9469952);     // 2,097,152  [16384][16][4]
  bf16* pooled = (bf16*)(ws + 11567104);   // 2,097,152  [16384][64]  (end 13,664,256)

  prep_kernel<<<1792, 256, 0, stream>>>(x, Wq, Wk, v, Wo, Wqb, Wkb, MmBg, Xt);
  gemm_q<<<dim3(128, 4), 256, 0, stream>>>(Xt, Wqb, bq, qpart);
  gemm_k<<<dim3(128, 8), 256, 0, stream>>>(Xt, Wkb, bk, qpart, pooled);
  out_kernel<<<256, 512, 0, stream>>>(pooled, MmBg, bo, x, out);
}

// Round 8
// 37.975 us; speedup vs baseline: 1.5303x; 1.5303x over previous
//
#include <hip/hip_runtime.h>
#include <hip/hip_bf16.h>
#include <stdint.h>

// B=4, C=256, H=W=64 -> L=4096, POS=16384; n_mem=64, sqrt_fin=16, scale=1/4.
using bf16 = __hip_bfloat16;
typedef __attribute__((ext_vector_type(8))) short bf16x8;
typedef __attribute__((ext_vector_type(4))) float f32x4;

#define CDIM 256
#define LDIM 4096

// LDS map (120 KiB)
// Xs    @0      : [64 p][256 k] bf16, 16B-unit XOR swizzle  (32 KB)
// rings @32768  : 8 waves x 8KB (4 granules x 2KB [16 o][64 k])  (64 KB)
//                 reused at end as Mlds [256 o2][64 n] (first 32 KB)
// QSW   @98304  : [64 p][16 s][8 w] bf16  (16 KB)
// pooled@114688 : [64 p][64 n] bf16, elem XOR swizzle  (8 KB)
#define RINGS_OFF 32768
#define QSW_OFF 98304
#define POOL_OFF 114688

__device__ __forceinline__ void gload16(void* lds, const void* g) {
  auto* l3 = (__attribute__((address_space(3))) char*)(uintptr_t)lds;
  auto* g1 = (const __attribute__((address_space(1))) char*)(uintptr_t)g;
  __builtin_amdgcn_global_load_lds((const __attribute__((address_space(1))) void*)g1,
                                   (__attribute__((address_space(3))) void*)l3, 16, 0, 0);
}

template <int CTRL>
__device__ __forceinline__ float dpp_add(float v) {
  int p = __builtin_amdgcn_update_dpp(0, __float_as_int(v), CTRL, 0xf, 0xf, true);
  return v + __int_as_float(p);
}

__device__ __forceinline__ float b2f(short h) {
  return __uint_as_float(((uint32_t)(uint16_t)h) << 16);
}

// ---------- prep: weight casts + MmB[o][n] = bf16(sum_c v[n][c]*Wo[o][c]) ----------
__global__ void prep_kernel(const float* __restrict__ Wq, const float* __restrict__ Wk,
                            const float* __restrict__ v, const float* __restrict__ Wo,
                            bf16* __restrict__ Wqb, bf16* __restrict__ Wkb,
                            bf16* __restrict__ MmBg) {
  int bid = blockIdx.x, t = threadIdx.x;
  if (bid < 512) {
    const float* src = (bid < 256) ? Wq : Wk;
    bf16* dst = (bid < 256) ? Wqb : Wkb;
    int base = (bid & 255) * 1024 + t * 4;
    float4 f = *(const float4*)(src + base);
    dst[base + 0] = __float2bfloat16(f.x);
    dst[base + 1] = __float2bfloat16(f.y);
    dst[base + 2] = __float2bfloat16(f.z);
    dst[base + 3] = __float2bfloat16(f.w);
  } else {
    __shared__ float red[256];
    int o = bid - 512;
    int n = t >> 2, cg = t & 3;
    const float* vr = v + n * CDIM + cg * 64;
    const float* wr = Wo + o * CDIM + cg * 64;
    float a = 0.f;
    for (int c = 0; c < 64; c++) a += vr[c] * wr[c];
    red[t] = a;
    __syncthreads();
    if (t < 64)
      MmBg[o * 64 + t] =
          __float2bfloat16(red[t * 4] + red[t * 4 + 1] + red[t * 4 + 2] + red[t * 4 + 3]);
  }
}

// stage granule for o-chunk `c` (runtime uniform, 0..15) into compile-time SLOT of this wave's ring
#define STAGE_G(c, SLOT)                                                                   \
  {                                                                                        \
    const char* wsrc_ = ((c) < 8) ? (const char*)Wqb : (const char*)Wkb;                   \
    int rowbase_ = w * 128 + ((c) & 7) * 16;                                               \
    _Pragma("unroll") for (int inst_ = 0; inst_ < 2; inst_++) {                            \
      int P_ = inst_ * 64 + lane;                                                          \
      int row_ = P_ >> 3, u_ = P_ & 7;                                                     \
      gload16((void*)(ringw + (SLOT) * 2048 + inst_ * 1024),                               \
              wsrc_ + (size_t)(rowbase_ + row_) * 512 + (SLOT) * 128 +                     \
                  ((u_ ^ (row_ & 7)) << 4));                                               \
    }                                                                                      \
  }

#define VMWAIT(N) asm volatile("s_waitcnt vmcnt(" #N ")" ::: "memory")

// one granule. Order matters:
//  1. lgkmcnt(0)+SB  -- proves previous GRAN's ds_read retired BEFORE the DMA
//                       that overwrites its slot can be enqueued (ring-reuse race fix)
//  2. stage granule +3 ahead
//  3. counted VMWAIT(WN)+SB, then ds_read + 8 MFMA
#define GRAN(GBASE, KQ, WN)                                                                \
  {                                                                                        \
    asm volatile("s_waitcnt lgkmcnt(0)" ::: "memory");                                     \
    __builtin_amdgcn_sched_barrier(0);                                                     \
    int tg_ = (GBASE) + ot * 4 + (KQ) + 3;                                                 \
    if (tg_ < 64) { int c_ = tg_ >> 2; STAGE_G(c_, (((KQ) + 3) & 3)); }                    \
    VMWAIT(WN);                                                                            \
    __builtin_amdgcn_sched_barrier(0);                                                     \
    _Pragma("unroll") for (int kt2_ = 0; kt2_ < 2; kt2_++) {                               \
      bf16x8 bf_ = *(const bf16x8*)(ringw + (KQ) * 2048 + s * 128 +                        \
                                    (((kt2_ * 4 + g) ^ (s & 7)) << 4));                    \
      _Pragma("unroll") for (int mf_ = 0; mf_ < 4; mf_++)                                  \
          acc[mf_] = __builtin_amdgcn_mfma_f32_16x16x32_bf16(                              \
              a_cache[mf_][(KQ) * 2 + kt2_], bf_, acc[mf_], 0, 0, 0);                      \
    }                                                                                      \
  }

// K-tile epilogue: DPP s-reduce + swizzled pooled write (uses acc, ot, qreg, ...)
#define K_EPI                                                                              \
  {                                                                                        \
    float bkv = bk[w * 128 + ot * 16 + s];                                                 \
    float red[16];                                                                         \
    _Pragma("unroll") for (int mf = 0; mf < 4; mf++)                                       \
        _Pragma("unroll") for (int r = 0; r < 4; r++) {                                    \
      float tt = qreg[mf][r] * fmaxf(acc[mf][r] + bkv, 0.f);                               \
      tt = dpp_add<0x128>(tt);                                                             \
      tt = dpp_add<0x124>(tt);                                                             \
      tt = dpp_add<0x122>(tt);                                                             \
      tt = dpp_add<0x121>(tt);                                                             \
      red[mf * 4 + r] = tt;                                                                \
    }                                                                                      \
    float a0 = (s & 1) ? red[1] : red[0];                                                  \
    float a1 = (s & 1) ? red[3] : red[2];                                                  \
    float a2 = (s & 1) ? red[5] : red[4];                                                  \
    float a3 = (s & 1) ? red[7] : red[6];                                                  \
    float a4 = (s & 1) ? red[9] : red[8];                                                  \
    float a5 = (s & 1) ? red[11] : red[10];                                                \
    float a6 = (s & 1) ? red[13] : red[12];                                                \
    float a7 = (s & 1) ? red[15] : red[14];                                                \
    float b0 = (s & 2) ? a1 : a0;                                                          \
    float b1 = (s & 2) ? a3 : a2;                                                          \
    float b2 = (s & 2) ? a5 : a4;                                                          \
    float b3 = (s & 2) ? a7 : a6;                                                          \
    float c0 = (s & 4) ? b1 : b0;                                                          \
    float c1 = (s & 4) ? b3 : b2;                                                          \
    float val = (s & 8) ? c1 : c0;                                                         \
    int pos_l = (s >> 2) * 16 + g * 4 + (s & 3);                                           \
    int n = w * 8 + ot;                                                                    \
    *(bf16*)(smem + POOL_OFF + pos_l * 128 + ((n ^ ((pos_l & 7) << 3)) * 2)) =             \
        __float2bfloat16(val);                                                             \
  }

__global__ __launch_bounds__(512, 2) void fused_kernel(
    const float* __restrict__ x, const bf16* __restrict__ Wqb, const bf16* __restrict__ Wkb,
    const float* __restrict__ bq, const float* __restrict__ bk,
    const bf16* __restrict__ MmBg, const float* __restrict__ bo, float* __restrict__ out) {
  __shared__ __align__(16) char smem[122880];
  const int tid = threadIdx.x;
  const int w = tid >> 6, lane = tid & 63;
  const int s = lane & 15, g = lane >> 4;
  const int pos0 = blockIdx.x * 64;
  const int bb = pos0 >> 12, l0 = pos0 & (LDIM - 1);
  char* ringw = smem + RINGS_OFF + w * 8192;

  // ---- prologue: prefetch this wave's first 3 granules (Q chunk 0, quarters 0..2) ----
  {
    int c0 = 0;
    STAGE_G(c0, 0);
    __builtin_amdgcn_sched_barrier(0);
    STAGE_G(c0, 1);
    __builtin_amdgcn_sched_barrier(0);
    STAGE_G(c0, 2);
    __builtin_amdgcn_sched_barrier(0);
  }
  // ---- X stage: x [C][L] f32 -> Xs [64 p][256 k] bf16, swizzled scatter ----
  // 4096 float4 slots = 256 k x 16 (p/4); 512 threads x 8 iterations
#pragma unroll
  for (int j = 0; j < 8; j++) {
    int slot = j * 512 + tid;
    int k = slot >> 4, p0 = (slot & 15) * 4;
    float4 f = *(const float4*)(x + ((size_t)bb * CDIM + k) * LDIM + l0 + p0);
    float fv[4] = {f.x, f.y, f.z, f.w};
#pragma unroll
    for (int jj = 0; jj < 4; jj++) {
      int p = p0 + jj;
      *(bf16*)(smem + p * 512 + (((k >> 3) ^ (p & 7)) << 4) + (k & 7) * 2) =
          __float2bfloat16(fv[jj]);
    }
  }
  asm volatile("s_waitcnt lgkmcnt(0)" ::: "memory");
  __builtin_amdgcn_s_barrier();
  __builtin_amdgcn_sched_barrier(0);

  // ---- A fragments -> registers: 32 x bf16x8 (held through Q and K loops) ----
  bf16x8 a_cache[4][8];
#pragma unroll
  for (int mf = 0; mf < 4; mf++) {
    int arow = mf * 16 + s;
#pragma unroll
    for (int kt = 0; kt < 8; kt++)
      a_cache[mf][kt] =
          *(const bf16x8*)(smem + arow * 512 + (((kt * 4 + g) ^ (arow & 7)) << 4));
  }

  // ================= Q projection: per-wave free-run, 8 o-tiles x 4 k-granules =================
  float qacc[4][4] = {};
#pragma unroll 1
  for (int ot = 0; ot < 8; ot++) {
    f32x4 acc[4] = {};
    GRAN(0, 0, 6) GRAN(0, 1, 6) GRAN(0, 2, 6) GRAN(0, 3, 6)
    float bqv = bq[w * 128 + ot * 16 + s];
#pragma unroll
    for (int mf = 0; mf < 4; mf++)
#pragma unroll
      for (int r = 0; r < 4; r++) qacc[mf][r] += fmaxf(acc[mf][r] + bqv, 0.f);
  }

  // ---- merge qsum across 8 waves via bf16 LDS ----
#pragma unroll
  for (int mf = 0; mf < 4; mf++)
#pragma unroll
    for (int r = 0; r < 4; r++) {
      int pos_l = mf * 16 + g * 4 + r;
      *(bf16*)(smem + QSW_OFF + ((pos_l * 16 + s) * 8 + w) * 2) = __float2bfloat16(qacc[mf][r]);
    }
  asm volatile("s_waitcnt lgkmcnt(0)" ::: "memory");
  __builtin_amdgcn_s_barrier();
  __builtin_amdgcn_sched_barrier(0);
  float qreg[4][4];
#pragma unroll
  for (int mf = 0; mf < 4; mf++)
#pragma unroll
    for (int r = 0; r < 4; r++) {
      int pos_l = mf * 16 + g * 4 + r;
      bf16x8 vv = *(const bf16x8*)(smem + QSW_OFF + (pos_l * 16 + s) * 16);
      float sum = 0.f;
#pragma unroll
      for (int j = 0; j < 8; j++) sum += b2f(vv[j]);
      qreg[mf][r] = 0.00390625f * sum;  // (1/4)/64
    }

  // ================= K projection: free-run ot=0..6, peeled ot=7 with tail-exact waits =================
#pragma unroll 1
  for (int ot = 0; ot < 7; ot++) {
    f32x4 acc[4] = {};
    GRAN(32, 0, 6) GRAN(32, 1, 6) GRAN(32, 2, 6) GRAN(32, 3, 6)
    K_EPI
  }
  {
    const int ot = 7;
    f32x4 acc[4] = {};
    GRAN(32, 0, 6) GRAN(32, 1, 4) GRAN(32, 2, 2) GRAN(32, 3, 0)
    K_EPI
  }

  // ---- join: rings dead (vmcnt 0 above), pooled written -> stage MmB into rings region ----
  asm volatile("s_waitcnt lgkmcnt(0)" ::: "memory");
  __builtin_amdgcn_s_barrier();
  __builtin_amdgcn_sched_barrier(0);
#pragma unroll
  for (int it = 0; it < 4; it++) {
    int P = it * 512 + tid;
    int row = P >> 3, u = P & 7;
    gload16((void*)(smem + RINGS_OFF + (it * 512 + w * 64) * 16),
            (const char*)MmBg + row * 128 + ((u ^ (row & 7)) << 4));
  }
  asm volatile("s_waitcnt vmcnt(0) lgkmcnt(0)" ::: "memory");
  __builtin_amdgcn_s_barrier();
  __builtin_amdgcn_sched_barrier(0);

  // ================= out = x + pooled @ MmB + bo =================
  {
    char* Mlds = smem + RINGS_OFF;  // [256 o2][64 n], swizzled
    char* Plds = smem + POOL_OFF;   // [64 pos][64 n], swizzled
    f32x4 oacc[2][4] = {};
#pragma unroll
    for (int kt = 0; kt < 2; kt++) {
      bf16x8 pf[4];
#pragma unroll
      for (int nfp = 0; nfp < 4; nfp++) {
        int prow = nfp * 16 + s;
        pf[nfp] = *(const bf16x8*)(Plds + prow * 128 + (((kt * 4 + g) ^ (prow & 7)) << 4));
      }
#pragma unroll
      for (int mfo = 0; mfo < 2; mfo++) {
        int mrow = w * 32 + mfo * 16 + s;
        bf16x8 mfr = *(const bf16x8*)(Mlds + mrow * 128 + (((kt * 4 + g) ^ (mrow & 7)) << 4));
#pragma unroll
        for (int nfp = 0; nfp < 4; nfp++)
          oacc[mfo][nfp] =
              __builtin_amdgcn_mfma_f32_16x16x32_bf16(mfr, pf[nfp], oacc[mfo][nfp], 0, 0, 0);
      }
    }
#pragma unroll
    for (int mfo = 0; mfo < 2; mfo++)
#pragma unroll
      for (int r = 0; r < 4; r++) {
        int o2 = w * 32 + mfo * 16 + g * 4 + r;
        float bov = bo[o2];
        const float* xr = x + ((size_t)(bb * CDIM + o2) * LDIM) + l0;
        float* orow = out + ((size_t)(bb * CDIM + o2) * LDIM) + l0;
#pragma unroll
        for (int nfp = 0; nfp < 4; nfp++) {
          int p = nfp * 16 + s;
          orow[p] = xr[p] + oacc[mfo][nfp][r] + bov;
        }
      }
  }
}

extern "C" void kernel_launch(void* const* d_in, const int* in_sizes, int n_in,
                              void* d_out, int out_size, void* d_ws, size_t ws_size,
                              hipStream_t stream) {
  (void)in_sizes; (void)n_in; (void)out_size; (void)ws_size;
  const float* x = (const float*)d_in[0];
  const float* Wq = (const float*)d_in[1];
  const float* bq = (const float*)d_in[2];
  const float* Wk = (const float*)d_in[3];
  const float* bk = (const float*)d_in[4];
  const float* v = (const float*)d_in[5];
  const float* Wo = (const float*)d_in[6];
  const float* bo = (const float*)d_in[7];
  float* out = (float*)d_out;

  char* ws = (char*)d_ws;
  bf16* Wqb = (bf16*)ws;                   // 524,288
  bf16* Wkb = (bf16*)(ws + 524288);        // 524,288
  bf16* MmBg = (bf16*)(ws + 1048576);      // 32,768  (end 1,081,344)

  prep_kernel<<<768, 256, 0, stream>>>(Wq, Wk, v, Wo, Wqb, Wkb, MmBg);
  fused_kernel<<<256, 512, 0, stream>>>(x, Wqb, Wkb, bq, bk, MmBg, bo, out);
}